// Round 1
// baseline (32807.635 us; speedup 1.0000x reference)
//
#include <hip/hip_runtime.h>

#define NN 1000
#define NP 1024

// Transpose S[NN][NN] (row-major) into ST[NP][NP] (column j of S -> row j of ST,
// contiguous over target-neuron index i). Padding zero-filled so the sim kernel
// needs no bounds checks on loads.
__global__ void transpose_S(const float* __restrict__ S, float* __restrict__ ST) {
    int idx = blockIdx.x * blockDim.x + threadIdx.x;
    if (idx >= NP * NP) return;
    int j = idx >> 10;        // source neuron (column of S)
    int i = idx & (NP - 1);   // target neuron (row of S)
    float val = (i < NN && j < NN) ? S[i * NN + j] : 0.0f;
    ST[(j << 10) + i] = val;
}

// Persistent single-block Izhikevich reservoir scan.
// 1024 threads = 16 waves on one CU; thread i owns neuron i.
__global__ void __launch_bounds__(1024) izhikevich_sim(
    const float* __restrict__ data, const float* __restrict__ U,
    const float* __restrict__ ST,
    const float* __restrict__ a, const float* __restrict__ b,
    const float* __restrict__ c, const float* __restrict__ d,
    const float* __restrict__ v0, const float* __restrict__ u0,
    float* __restrict__ out_states, float* __restrict__ out_v,
    float* __restrict__ out_u, float* __restrict__ out_fir, int T)
{
    __shared__ unsigned long long masks[16];
    __shared__ int fired_idx[NP];

    const int i = threadIdx.x;
    const int w = i >> 6;
    const int lane = i & 63;
    const bool act = (i < NN);

    float v = act ? v0[i] : -50.0f;
    float u = act ? u0[i] : 0.0f;
    const float ai = act ? a[i] : 0.0f;
    const float bi = act ? b[i] : 0.0f;
    const float ci = act ? c[i] : 0.0f;
    const float di = act ? d[i] : 0.0f;
    const float Ui = act ? U[i] : 0.0f;

    bool fired = (v >= 30.0f);   // v0 = -50 -> false at t=0

    for (int t = 0; t < T; ++t) {
        // --- publish fired mask (deterministic, no atomics) ---
        unsigned long long m = __ballot(fired);
        if (lane == 0) masks[w] = m;
        __syncthreads();

        // per-thread exclusive prefix over wave masks -> compact position
        int K = 0, base = 0;
        #pragma unroll
        for (int ww = 0; ww < 16; ++ww) {
            int p = __popcll(masks[ww]);
            if (ww < w) base += p;
            K += p;
        }
        if (fired) {
            int pos = base + __popcll(m & ((1ull << lane) - 1ull));
            fired_idx[pos] = i;
            // reference applies reset twice: v=c (idempotent), u += 2*d
            v = ci;
            u += 2.0f * di;
        }
        __syncthreads();

        if (act) {
            // I = x_t * U + S @ fm  (gather fired columns, coalesced via ST)
            float I = data[t] * Ui;
            int k = 0;
            for (; k + 3 < K; k += 4) {
                int j0 = fired_idx[k + 0] << 10;
                int j1 = fired_idx[k + 1] << 10;
                int j2 = fired_idx[k + 2] << 10;
                int j3 = fired_idx[k + 3] << 10;
                float s0 = ST[j0 + i];
                float s1 = ST[j1 + i];
                float s2 = ST[j2 + i];
                float s3 = ST[j3 + i];
                I += s0; I += s1; I += s2; I += s3;
            }
            for (; k < K; ++k) I += ST[(fired_idx[k] << 10) + i];

            v = v + 0.5f * (0.04f * v * v + 5.0f * v + 140.0f - u + I);
            u = u + ai * (bi * v - u);
            bool nf = (v >= 30.0f);
            out_states[(size_t)t * NN + i] = nf ? 1.0f : 0.0f;
            out_fir[(size_t)t * NN + i]   = fired ? 1.0f : 0.0f;
            fired = nf;
        }
        __syncthreads();   // protect masks/fired_idx before next iteration
    }

    if (act) { out_v[i] = v; out_u[i] = u; }
}

extern "C" void kernel_launch(void* const* d_in, const int* in_sizes, int n_in,
                              void* d_out, int out_size, void* d_ws, size_t ws_size,
                              hipStream_t stream) {
    const float* data = (const float*)d_in[0];
    const float* U    = (const float*)d_in[1];
    const float* S    = (const float*)d_in[2];
    const float* a    = (const float*)d_in[3];
    const float* b    = (const float*)d_in[4];
    const float* c    = (const float*)d_in[5];
    const float* dd   = (const float*)d_in[6];
    const float* v0   = (const float*)d_in[7];
    const float* u0   = (const float*)d_in[8];
    const int T = in_sizes[0];   // 16384

    float* ST = (float*)d_ws;    // NP*NP*4 = 4 MB scratch

    float* out        = (float*)d_out;
    float* out_states = out;                          // [T, NN]
    float* out_v      = out + (size_t)T * NN;         // [NN]
    float* out_u      = out_v + NN;                   // [NN]
    float* out_fir    = out_u + NN;                   // [T, NN]

    hipLaunchKernelGGL(transpose_S, dim3((NP * NP) / 256), dim3(256), 0, stream, S, ST);
    hipLaunchKernelGGL(izhikevich_sim, dim3(1), dim3(1024), 0, stream,
                       data, U, ST, a, b, c, dd, v0, u0,
                       out_states, out_v, out_u, out_fir, T);
}